// Round 9
// baseline (127.770 us; speedup 1.0000x reference)
//
#include <hip/hip_runtime.h>

// Problem constants (B=2, S=512, D=128, DG=64, NG=2)
#define BQ 2
#define SQ 512
#define DQ 128
#define DGQ 64
#define NGQ 2

// ws layout (floats):
//   QW1 : [B*S][128]          @ 0        (= (x@Wq)@blkdiag(W1) + b1, per group)
//   KW1 : [B*S][128]          @ 131072
//   Vp  : [B*S][NG][DG]       @ 262144   (group-major V for coalesced A@V)

// ---------------------------------------------------------------------------
// Kernel 1: fused projections (unchanged — fp32 exact).
// ---------------------------------------------------------------------------
__global__ __launch_bounds__(256) void proj_kernel(
    const float* __restrict__ x,
    const float* __restrict__ Wq, const float* __restrict__ Wk,
    const float* __restrict__ Wv,
    const float* __restrict__ W1, const float* __restrict__ b1,
    float* __restrict__ QW1, float* __restrict__ KW1, float* __restrict__ Vp)
{
    const int t = threadIdx.x;
    const int row = blockIdx.x;            // flat b*S+s, 1024 rows
    __shared__ float xs[DQ];
    __shared__ float part[3][2][DQ];
    __shared__ float qs[DQ], ks[DQ];

    if (t < DQ) xs[t] = x[(size_t)row * DQ + t];
    __syncthreads();

    const int f = t & 127, h = t >> 7;
    float aq = 0.f, ak = 0.f, av = 0.f;
    const int d0 = h * 64;
    #pragma unroll 8
    for (int d = 0; d < 64; ++d) {
        const float xv = xs[d0 + d];
        const size_t o = (size_t)(d0 + d) * DQ + f;
        aq = fmaf(xv, Wq[o], aq);
        ak = fmaf(xv, Wk[o], ak);
        av = fmaf(xv, Wv[o], av);
    }
    part[0][h][f] = aq; part[1][h][f] = ak; part[2][h][f] = av;
    __syncthreads();

    if (t < DQ) {
        qs[t] = part[0][0][t] + part[0][1][t];
        const float v = part[2][0][t] + part[2][1][t];
        Vp[((size_t)row * NGQ + (t & 1)) * DGQ + (t >> 1)] = v;
    } else {
        const int f2 = t - DQ;
        ks[f2] = part[1][0][f2] + part[1][1][f2];
    }
    __syncthreads();

    const int fb = t & 127, side = t >> 7;
    const int g = fb >> 6, c = fb & 63;
    const float* src = side ? ks : qs;
    float acc = side ? 0.f : b1[c];
    #pragma unroll 8
    for (int e = 0; e < 64; ++e)
        acc = fmaf(src[g * 64 + e], W1[e * DGQ + c], acc);
    (side ? KW1 : QW1)[(size_t)row * DQ + fb] = acc;
}

// ---------------------------------------------------------------------------
// Kernel 2: one block per (b, g, query-pair); 512 thr, thread t = key j.
// R7 insight: v_pk_fma_f32 is half-rate (157 TF spec has no packed doubling)
// so fp32 packing was a no-op; the real deficit is the 2.3x stall factor
// from in-loop LDS q-reads (~120cy each, 64/thread). Fix: q is BLOCK-UNIFORM
// -> read through uniform pointers with constant indices so the compiler
// emits s_load (SGPR, scalar cache). Hot loop has zero LDS traffic; only
// 4-deep prefetched krow float4 loads. 2-query tile (R4's best geometry):
// 1024 blocks, VGPR target ~70 -> 3 blocks/CU, 24 waves.
// ---------------------------------------------------------------------------
__global__ __launch_bounds__(512) void attn_kernel(
    const float* __restrict__ QW1, const float* __restrict__ KW1,
    const float* __restrict__ Vp,
    const float* __restrict__ W2, const float* __restrict__ b2,
    const float* __restrict__ W3, const float* __restrict__ b3,
    const float* __restrict__ pos_add, const float* __restrict__ pos_mul,
    float* __restrict__ out)
{
    const int t = threadIdx.x;                  // key index j
    const int ipair = blockIdx.x & 255;
    const int g = (blockIdx.x >> 8) & 1;
    const int b = blockIdx.x >> 9;
    const int i0 = ipair * 2;
    const int lane = t & 63, wv = t >> 6;

    __shared__ __align__(8) float sc[SQ * 2];      // interleaved {e0,e1} per key
    __shared__ float redm[2][8], reds[2][8];
    __shared__ float avs[2][8][DGQ];

    // block-uniform pointers -> scalar (s_load) accesses, no LDS staging
    const float* __restrict__ q0 = QW1 + ((size_t)(b * SQ + i0)) * DQ + g * DGQ;
    const float* __restrict__ q1 = q0 + DQ;

    const float4* krow = reinterpret_cast<const float4*>(
        KW1 + ((size_t)(b * SQ + t)) * DQ + g * DGQ);

    float acc0[16], acc1[16];
    #pragma unroll
    for (int o = 0; o < 16; ++o) { acc0[o] = b2[o]; acc1[o] = b2[o]; }

    float4 kbuf[4];
    #pragma unroll
    for (int p = 0; p < 4; ++p) kbuf[p] = krow[p];

    #pragma unroll
    for (int c4 = 0; c4 < 16; ++c4) {
        const float4 kv = kbuf[c4 & 3];
        if (c4 < 12) kbuf[c4 & 3] = krow[c4 + 4];   // 4-deep rolling prefetch
        // h1 for both queries, 4 channels (q* are SGPR values)
        const float h00 = fmaxf(q0[c4 * 4 + 0] - kv.x, 0.f);
        const float h01 = fmaxf(q0[c4 * 4 + 1] - kv.y, 0.f);
        const float h02 = fmaxf(q0[c4 * 4 + 2] - kv.z, 0.f);
        const float h03 = fmaxf(q0[c4 * 4 + 3] - kv.w, 0.f);
        const float h10 = fmaxf(q1[c4 * 4 + 0] - kv.x, 0.f);
        const float h11 = fmaxf(q1[c4 * 4 + 1] - kv.y, 0.f);
        const float h12 = fmaxf(q1[c4 * 4 + 2] - kv.z, 0.f);
        const float h13 = fmaxf(q1[c4 * 4 + 3] - kv.w, 0.f);
        const float* w2r = W2 + c4 * 64;            // uniform -> SGPR
        #pragma unroll
        for (int o = 0; o < 16; ++o) {
            const float w0 = w2r[o], w1 = w2r[16 + o];
            const float w2_ = w2r[32 + o], w3_ = w2r[48 + o];
            acc0[o] = fmaf(h00, w0, acc0[o]);
            acc0[o] = fmaf(h01, w1, acc0[o]);
            acc0[o] = fmaf(h02, w2_, acc0[o]);
            acc0[o] = fmaf(h03, w3_, acc0[o]);
            acc1[o] = fmaf(h10, w0, acc1[o]);
            acc1[o] = fmaf(h11, w1, acc1[o]);
            acc1[o] = fmaf(h12, w2_, acc1[o]);
            acc1[o] = fmaf(h13, w3_, acc1[o]);
        }
    }

    // positional bias AFTER the hot loop (registers not live across it)
    const size_t bo0 = ((size_t)g * SQ + i0) * SQ + t;
    const float pm0 = pos_mul[bo0],      pa0 = pos_add[bo0];
    const float pm1 = pos_mul[bo0 + SQ], pa1 = pos_add[bo0 + SQ];

    // layer 3 + bias -> logits
    float a0 = b3[0], a1 = b3[0];
    #pragma unroll
    for (int o = 0; o < 16; ++o) {
        a0 = fmaf(fmaxf(acc0[o], 0.f), W3[o], a0);
        a1 = fmaf(fmaxf(acc1[o], 0.f), W3[o], a1);
    }
    const float logit0 = fmaf(fmaxf(a0, 0.f), pm0, pa0);
    const float logit1 = fmaf(fmaxf(a1, 0.f), pm1, pa1);

    // ---- softmax for both queries (logits in-register) ----
    float m0 = logit0, m1 = logit1;
    #pragma unroll
    for (int off = 32; off > 0; off >>= 1) {
        m0 = fmaxf(m0, __shfl_xor(m0, off));
        m1 = fmaxf(m1, __shfl_xor(m1, off));
    }
    if (lane == 0) { redm[0][wv] = m0; redm[1][wv] = m1; }
    __syncthreads();
    float M0 = redm[0][0], M1 = redm[1][0];
    #pragma unroll
    for (int w = 1; w < 8; ++w) {
        M0 = fmaxf(M0, redm[0][w]); M1 = fmaxf(M1, redm[1][w]);
    }
    const float e0 = __expf(logit0 - M0);
    const float e1 = __expf(logit1 - M1);
    sc[t * 2] = e0; sc[t * 2 + 1] = e1;
    float s0 = e0, s1 = e1;
    #pragma unroll
    for (int off = 32; off > 0; off >>= 1) {
        s0 += __shfl_xor(s0, off);
        s1 += __shfl_xor(s1, off);
    }
    if (lane == 0) { reds[0][wv] = s0; reds[1][wv] = s1; }
    __syncthreads();
    float S0 = 0.f, S1 = 0.f;
    #pragma unroll
    for (int w = 0; w < 8; ++w) { S0 += reds[0][w]; S1 += reds[1][w]; }
    const float inv0 = 1.f / S0, inv1 = 1.f / S1;

    // ---- A@V: wave wv covers keys wv*64..+63; lane = dim; V shared x2 ----
    const float* vbase = Vp + (((size_t)(b * SQ + wv * 64)) * NGQ + g) * DGQ + lane;
    float av0 = 0.f, av1 = 0.f;
    #pragma unroll 16
    for (int k = 0; k < 64; ++k) {
        const float v = vbase[(size_t)k * (NGQ * DGQ)];
        const int ks = (wv * 64 + k) * 2;
        av0 = fmaf(v, sc[ks], av0);          // wave-uniform LDS broadcast
        av1 = fmaf(v, sc[ks + 1], av1);
    }
    avs[0][wv][lane] = av0;
    avs[1][wv][lane] = av1;
    __syncthreads();
    if (t < 2 * DGQ) {
        const int qq = t >> 6, d = t & 63;
        float sum = 0.f;
        #pragma unroll
        for (int w = 0; w < 8; ++w) sum += avs[qq][w][d];
        out[((size_t)(b * SQ + i0 + qq)) * DQ + d * NGQ + g] =
            sum * (qq ? inv1 : inv0);
    }
}

extern "C" void kernel_launch(void* const* d_in, const int* in_sizes, int n_in,
                              void* d_out, int out_size, void* d_ws, size_t ws_size,
                              hipStream_t stream) {
    const float* x       = (const float*)d_in[0];
    const float* pos_add = (const float*)d_in[1];
    const float* pos_mul = (const float*)d_in[2];
    const float* Wq      = (const float*)d_in[3];
    const float* Wk      = (const float*)d_in[4];
    const float* Wv      = (const float*)d_in[5];
    const float* W1      = (const float*)d_in[6];
    const float* b1      = (const float*)d_in[7];
    const float* W2      = (const float*)d_in[8];
    const float* b2      = (const float*)d_in[9];
    const float* W3      = (const float*)d_in[10];
    const float* b3      = (const float*)d_in[11];
    float* out = (float*)d_out;

    float* ws  = (float*)d_ws;
    float* QW1 = ws;
    float* KW1 = ws + 131072;
    float* Vp  = ws + 262144;

    proj_kernel<<<BQ * SQ, 256, 0, stream>>>(x, Wq, Wk, Wv, W1, b1,
                                             QW1, KW1, Vp);
    attn_kernel<<<BQ * NGQ * SQ / 2, 512, 0, stream>>>(QW1, KW1, Vp, W2, b2,
                                                       W3, b3, pos_add, pos_mul,
                                                       out);
}

// Round 10
// 122.863 us; speedup vs baseline: 1.0399x; 1.0399x over previous
//
#include <hip/hip_runtime.h>

// Problem constants (B=2, S=512, D=128, DG=64, NG=2)
#define BQ 2
#define SQ 512
#define DQ 128
#define DGQ 64
#define NGQ 2

typedef float float2v __attribute__((ext_vector_type(2)));

// ws layout (floats):
//   QW1 : [B*S][128]          @ 0        (= (x@Wq)@blkdiag(W1) + b1, per group)
//   KW1 : [B*S][128]          @ 131072
//   Vp  : [B*S][NG][DG]       @ 262144   (group-major V for coalesced A@V)

// ---------------------------------------------------------------------------
// Kernel 1: fused projections (unchanged — fp32 exact).
// ---------------------------------------------------------------------------
__global__ __launch_bounds__(256) void proj_kernel(
    const float* __restrict__ x,
    const float* __restrict__ Wq, const float* __restrict__ Wk,
    const float* __restrict__ Wv,
    const float* __restrict__ W1, const float* __restrict__ b1,
    float* __restrict__ QW1, float* __restrict__ KW1, float* __restrict__ Vp)
{
    const int t = threadIdx.x;
    const int row = blockIdx.x;            // flat b*S+s, 1024 rows
    __shared__ float xs[DQ];
    __shared__ float part[3][2][DQ];
    __shared__ float qs[DQ], ks[DQ];

    if (t < DQ) xs[t] = x[(size_t)row * DQ + t];
    __syncthreads();

    const int f = t & 127, h = t >> 7;
    float aq = 0.f, ak = 0.f, av = 0.f;
    const int d0 = h * 64;
    #pragma unroll 8
    for (int d = 0; d < 64; ++d) {
        const float xv = xs[d0 + d];
        const size_t o = (size_t)(d0 + d) * DQ + f;
        aq = fmaf(xv, Wq[o], aq);
        ak = fmaf(xv, Wk[o], ak);
        av = fmaf(xv, Wv[o], av);
    }
    part[0][h][f] = aq; part[1][h][f] = ak; part[2][h][f] = av;
    __syncthreads();

    if (t < DQ) {
        qs[t] = part[0][0][t] + part[0][1][t];
        const float v = part[2][0][t] + part[2][1][t];
        Vp[((size_t)row * NGQ + (t & 1)) * DGQ + (t >> 1)] = v;
    } else {
        const int f2 = t - DQ;
        ks[f2] = part[1][0][f2] + part[1][1][f2];
    }
    __syncthreads();

    const int fb = t & 127, side = t >> 7;
    const int g = fb >> 6, c = fb & 63;
    const float* src = side ? ks : qs;
    float acc = side ? 0.f : b1[c];
    #pragma unroll 8
    for (int e = 0; e < 64; ++e)
        acc = fmaf(src[g * 64 + e], W1[e * DGQ + c], acc);
    (side ? KW1 : QW1)[(size_t)row * DQ + fb] = acc;
}

// ---------------------------------------------------------------------------
// Kernel 2: one block per (b, g, query-pair); 512 thr, thread t = key j.
// R7+R9 synthesis: total VALU-issue time was 19-20 us with pk math (R3/R7)
// vs 32.4 us scalar (R9) -> v_pk_fma_f32 DOES halve issue cycles (R7 theory
// wrong). R9 separately proved SGPR-q (uniform pointers, no in-loop LDS)
// cuts stall time 24 -> 13 us. This kernel combines both: R3's pk inner
// loop + R9's scalar q + 4-deep krow register prefetch.
// ---------------------------------------------------------------------------
__global__ __launch_bounds__(512) void attn_kernel(
    const float* __restrict__ QW1, const float* __restrict__ KW1,
    const float* __restrict__ Vp,
    const float* __restrict__ W2, const float* __restrict__ b2,
    const float* __restrict__ W3, const float* __restrict__ b3,
    const float* __restrict__ pos_add, const float* __restrict__ pos_mul,
    float* __restrict__ out)
{
    const int t = threadIdx.x;                  // key index j
    const int ipair = blockIdx.x & 255;
    const int g = (blockIdx.x >> 8) & 1;
    const int b = blockIdx.x >> 9;
    const int i0 = ipair * 2;
    const int lane = t & 63, wv = t >> 6;

    __shared__ __align__(8) float sc[SQ * 2];      // interleaved {e0,e1} per key
    __shared__ float redm[2][8], reds[2][8];
    __shared__ float avs[2][8][DGQ];

    // block-uniform pointers -> s_load (scalar cache), no LDS staging
    const float* __restrict__ q0 = QW1 + ((size_t)(b * SQ + i0)) * DQ + g * DGQ;
    const float* __restrict__ q1 = q0 + DQ;

    const float4* krow = reinterpret_cast<const float4*>(
        KW1 + ((size_t)(b * SQ + t)) * DQ + g * DGQ);
    const float2v* b2v = reinterpret_cast<const float2v*>(b2);
    const float2v zero2 = {0.f, 0.f};

    float2v acc0[8], acc1[8];
    #pragma unroll
    for (int o = 0; o < 8; ++o) { acc0[o] = b2v[o]; acc1[o] = b2v[o]; }

    float4 kbuf[4];
    #pragma unroll
    for (int p = 0; p < 4; ++p) kbuf[p] = krow[p];

    #pragma unroll
    for (int c4 = 0; c4 < 16; ++c4) {
        const float4 kv = kbuf[c4 & 3];
        if (c4 < 12) kbuf[c4 & 3] = krow[c4 + 4];   // 4-deep rolling prefetch
        const float2v k01 = {kv.x, kv.y}, k23 = {kv.z, kv.w};
        // q channels come from SGPRs (uniform); h in pk form (v_pk_sub/max)
        const float2v ha01 = __builtin_elementwise_max(
            float2v{q0[c4 * 4 + 0], q0[c4 * 4 + 1]} - k01, zero2);
        const float2v ha23 = __builtin_elementwise_max(
            float2v{q0[c4 * 4 + 2], q0[c4 * 4 + 3]} - k23, zero2);
        const float2v hb01 = __builtin_elementwise_max(
            float2v{q1[c4 * 4 + 0], q1[c4 * 4 + 1]} - k01, zero2);
        const float2v hb23 = __builtin_elementwise_max(
            float2v{q1[c4 * 4 + 2], q1[c4 * 4 + 3]} - k23, zero2);
        const float2v* w2r = reinterpret_cast<const float2v*>(W2 + c4 * 64);
        #pragma unroll
        for (int o = 0; o < 8; ++o) {
            const float2v w0 = w2r[o],      w1 = w2r[8 + o];    // SGPR
            const float2v w2_ = w2r[16 + o], w3_ = w2r[24 + o];
            acc0[o] += ha01.x * w0;  acc0[o] += ha01.y * w1;    // v_pk_fma
            acc0[o] += ha23.x * w2_; acc0[o] += ha23.y * w3_;
            acc1[o] += hb01.x * w0;  acc1[o] += hb01.y * w1;
            acc1[o] += hb23.x * w2_; acc1[o] += hb23.y * w3_;
        }
    }

    // positional bias AFTER the hot loop (registers not live across it)
    const size_t bo0 = ((size_t)g * SQ + i0) * SQ + t;
    const float pm0 = pos_mul[bo0],      pa0 = pos_add[bo0];
    const float pm1 = pos_mul[bo0 + SQ], pa1 = pos_add[bo0 + SQ];

    // layer 3 + bias -> logits
    float a0 = b3[0], a1 = b3[0];
    #pragma unroll
    for (int o = 0; o < 8; ++o) {
        a0 = fmaf(fmaxf(acc0[o].x, 0.f), W3[2 * o], a0);
        a0 = fmaf(fmaxf(acc0[o].y, 0.f), W3[2 * o + 1], a0);
        a1 = fmaf(fmaxf(acc1[o].x, 0.f), W3[2 * o], a1);
        a1 = fmaf(fmaxf(acc1[o].y, 0.f), W3[2 * o + 1], a1);
    }
    const float logit0 = fmaf(fmaxf(a0, 0.f), pm0, pa0);
    const float logit1 = fmaf(fmaxf(a1, 0.f), pm1, pa1);

    // ---- softmax for both queries (logits in-register) ----
    float m0 = logit0, m1 = logit1;
    #pragma unroll
    for (int off = 32; off > 0; off >>= 1) {
        m0 = fmaxf(m0, __shfl_xor(m0, off));
        m1 = fmaxf(m1, __shfl_xor(m1, off));
    }
    if (lane == 0) { redm[0][wv] = m0; redm[1][wv] = m1; }
    __syncthreads();
    float M0 = redm[0][0], M1 = redm[1][0];
    #pragma unroll
    for (int w = 1; w < 8; ++w) {
        M0 = fmaxf(M0, redm[0][w]); M1 = fmaxf(M1, redm[1][w]);
    }
    const float e0 = __expf(logit0 - M0);
    const float e1 = __expf(logit1 - M1);
    *reinterpret_cast<float2v*>(&sc[t * 2]) = float2v{e0, e1};
    float s0 = e0, s1 = e1;
    #pragma unroll
    for (int off = 32; off > 0; off >>= 1) {
        s0 += __shfl_xor(s0, off);
        s1 += __shfl_xor(s1, off);
    }
    if (lane == 0) { reds[0][wv] = s0; reds[1][wv] = s1; }
    __syncthreads();
    float S0 = 0.f, S1 = 0.f;
    #pragma unroll
    for (int w = 0; w < 8; ++w) { S0 += reds[0][w]; S1 += reds[1][w]; }
    const float inv0 = 1.f / S0, inv1 = 1.f / S1;

    // ---- A@V: wave wv covers keys wv*64..+63; lane = dim; V shared x2 ----
    const float* vbase = Vp + (((size_t)(b * SQ + wv * 64)) * NGQ + g) * DGQ + lane;
    float av0 = 0.f, av1 = 0.f;
    #pragma unroll 16
    for (int k = 0; k < 64; ++k) {
        const float v = vbase[(size_t)k * (NGQ * DGQ)];
        const int ks = (wv * 64 + k) * 2;
        av0 = fmaf(v, sc[ks], av0);          // wave-uniform LDS broadcast
        av1 = fmaf(v, sc[ks + 1], av1);
    }
    avs[0][wv][lane] = av0;
    avs[1][wv][lane] = av1;
    __syncthreads();
    if (t < 2 * DGQ) {
        const int qq = t >> 6, d = t & 63;
        float sum = 0.f;
        #pragma unroll
        for (int w = 0; w < 8; ++w) sum += avs[qq][w][d];
        out[((size_t)(b * SQ + i0 + qq)) * DQ + d * NGQ + g] =
            sum * (qq ? inv1 : inv0);
    }
}

extern "C" void kernel_launch(void* const* d_in, const int* in_sizes, int n_in,
                              void* d_out, int out_size, void* d_ws, size_t ws_size,
                              hipStream_t stream) {
    const float* x       = (const float*)d_in[0];
    const float* pos_add = (const float*)d_in[1];
    const float* pos_mul = (const float*)d_in[2];
    const float* Wq      = (const float*)d_in[3];
    const float* Wk      = (const float*)d_in[4];
    const float* Wv      = (const float*)d_in[5];
    const float* W1      = (const float*)d_in[6];
    const float* b1      = (const float*)d_in[7];
    const float* W2      = (const float*)d_in[8];
    const float* b2      = (const float*)d_in[9];
    const float* W3      = (const float*)d_in[10];
    const float* b3      = (const float*)d_in[11];
    float* out = (float*)d_out;

    float* ws  = (float*)d_ws;
    float* QW1 = ws;
    float* KW1 = ws + 131072;
    float* Vp  = ws + 262144;

    proj_kernel<<<BQ * SQ, 256, 0, stream>>>(x, Wq, Wk, Wv, W1, b1,
                                             QW1, KW1, Vp);
    attn_kernel<<<BQ * NGQ * SQ / 2, 512, 0, stream>>>(QW1, KW1, Vp, W2, b2,
                                                       W3, b3, pos_add, pos_mul,
                                                       out);
}